// Round 1
// baseline (432.393 us; speedup 1.0000x reference)
//
#include <hip/hip_runtime.h>
#include <hip/hip_fp16.h>

// PostGammaDenoise: guided-filter luma smoothing, r=8 (17x17 box), eps=0.005.
// Two passes: (Y,Y^2) -> box -> (a,b) [stored fp16x2 in ws],
//             (a,b)  -> box -> scale -> out.

#define HH 4096
#define WW 4096
#define RR 8
#define TILE 64
#define LD 80            // TILE + 2*RR
#define SY_STRIDE 81     // 80-wide staging rows, +1 pad: 2-way max bank aliasing
#define H_STRIDE 65      // 64-wide intermediate rows, +1 pad: avoids 32-way conflict
#define INV289 (1.0f / 289.0f)
#define EPSV 0.005f

__device__ __forceinline__ int reflect_idx(int i, int n) {
    i = (i < 0) ? -i : i;
    i = (i >= n) ? (2 * n - 2 - i) : i;
    return i;
}

__global__ __launch_bounds__(256) void gf_pass1(const float* __restrict__ x,
                                                __half2* __restrict__ ab) {
    __shared__ float sY[LD * SY_STRIDE];
    __shared__ float hI[LD * H_STRIDE];
    __shared__ float hII[LD * H_STRIDE];
    const int t = threadIdx.x;
    const int tx = blockIdx.x * TILE;
    const int ty = blockIdx.y * TILE;

    // Stage luma for the 80x80 halo tile.
    for (int i = t; i < LD * LD; i += 256) {
        int r = i / LD, c = i - r * LD;
        int gy = reflect_idx(ty + r - RR, HH);
        int gx = reflect_idx(tx + c - RR, WW);
        const float* p = x + (gy * WW + gx) * 3;
        sY[r * SY_STRIDE + c] = 0.2126f * p[0] + 0.7152f * p[1] + 0.0722f * p[2];
    }
    __syncthreads();

    // Horizontal box (width 17) of Y and Y^2: 80 rows x 4 segments of 16,
    // register sliding window (~2 LDS reads per output).
    for (int task = t; task < LD * 4; task += 256) {
        int r = task >> 2, s = task & 3;
        int base = r * SY_STRIDE + s * 16;
        int ob = r * H_STRIDE + s * 16;
        float sI = 0.f, sII = 0.f;
        #pragma unroll
        for (int k = 0; k <= 16; ++k) { float v = sY[base + k]; sI += v; sII += v * v; }
        hI[ob] = sI; hII[ob] = sII;
        #pragma unroll
        for (int j = 1; j < 16; ++j) {
            float va = sY[base + 16 + j];
            float vs = sY[base + j - 1];
            sI  += va - vs;
            sII += va * va - vs * vs;
            hI[ob + j] = sI; hII[ob + j] = sII;
        }
    }
    __syncthreads();

    // Vertical box (height 17) + a,b computation + fp16x2 store.
    const int col = t & 63;
    const int y0 = (t >> 6) * 16;
    float sI = 0.f, sII = 0.f;
    #pragma unroll
    for (int k = 0; k <= 16; ++k) {
        sI  += hI[(y0 + k) * H_STRIDE + col];
        sII += hII[(y0 + k) * H_STRIDE + col];
    }
    #pragma unroll
    for (int j = 0; j < 16; ++j) {
        float mI = sI * INV289;
        float mII = sII * INV289;
        float var = mII - mI * mI;
        float a = var / (var + EPSV);
        float b = mI - a * mI;
        ab[(ty + y0 + j) * WW + (tx + col)] = __floats2half2_rn(a, b);
        if (j < 15) {
            sI  += hI[(y0 + j + 17) * H_STRIDE + col] - hI[(y0 + j) * H_STRIDE + col];
            sII += hII[(y0 + j + 17) * H_STRIDE + col] - hII[(y0 + j) * H_STRIDE + col];
        }
    }
}

__global__ __launch_bounds__(256) void gf_pass2(const float* __restrict__ x,
                                                const __half2* __restrict__ ab,
                                                float* __restrict__ out) {
    __shared__ __half2 sAB[LD * SY_STRIDE];
    __shared__ float hA[LD * H_STRIDE];
    __shared__ float hB[LD * H_STRIDE];
    const int t = threadIdx.x;
    const int tx = blockIdx.x * TILE;
    const int ty = blockIdx.y * TILE;

    for (int i = t; i < LD * LD; i += 256) {
        int r = i / LD, c = i - r * LD;
        int gy = reflect_idx(ty + r - RR, HH);
        int gx = reflect_idx(tx + c - RR, WW);
        sAB[r * SY_STRIDE + c] = ab[gy * WW + gx];
    }
    __syncthreads();

    for (int task = t; task < LD * 4; task += 256) {
        int r = task >> 2, s = task & 3;
        int base = r * SY_STRIDE + s * 16;
        int ob = r * H_STRIDE + s * 16;
        float sA = 0.f, sB = 0.f;
        #pragma unroll
        for (int k = 0; k <= 16; ++k) {
            __half2 v = sAB[base + k];
            sA += __low2float(v); sB += __high2float(v);
        }
        hA[ob] = sA; hB[ob] = sB;
        #pragma unroll
        for (int j = 1; j < 16; ++j) {
            __half2 va = sAB[base + 16 + j];
            __half2 vs = sAB[base + j - 1];
            sA += __low2float(va)  - __low2float(vs);
            sB += __high2float(va) - __high2float(vs);
            hA[ob + j] = sA; hB[ob + j] = sB;
        }
    }
    __syncthreads();

    const int col = t & 63;
    const int y0 = (t >> 6) * 16;
    float sA = 0.f, sB = 0.f;
    #pragma unroll
    for (int k = 0; k <= 16; ++k) {
        sA += hA[(y0 + k) * H_STRIDE + col];
        sB += hB[(y0 + k) * H_STRIDE + col];
    }
    #pragma unroll
    for (int j = 0; j < 16; ++j) {
        float ma = sA * INV289;
        float mb = sB * INV289;
        int gy = ty + y0 + j, gx = tx + col;
        const float* p = x + (gy * WW + gx) * 3;
        float r0 = p[0], g0 = p[1], b0 = p[2];
        float Y = 0.2126f * r0 + 0.7152f * g0 + 0.0722f * b0;
        float scale = (ma * Y + mb) / fmaxf(Y, 1e-6f);
        float* q = out + (gy * WW + gx) * 3;
        q[0] = fminf(fmaxf(r0 * scale, 0.f), 1.f);
        q[1] = fminf(fmaxf(g0 * scale, 0.f), 1.f);
        q[2] = fminf(fmaxf(b0 * scale, 0.f), 1.f);
        if (j < 15) {
            sA += hA[(y0 + j + 17) * H_STRIDE + col] - hA[(y0 + j) * H_STRIDE + col];
            sB += hB[(y0 + j + 17) * H_STRIDE + col] - hB[(y0 + j) * H_STRIDE + col];
        }
    }
}

extern "C" void kernel_launch(void* const* d_in, const int* in_sizes, int n_in,
                              void* d_out, int out_size, void* d_ws, size_t ws_size,
                              hipStream_t stream) {
    const float* x = (const float*)d_in[0];
    float* out = (float*)d_out;
    __half2* ab = (__half2*)d_ws;   // 4096*4096*4 B = 64 MB of scratch
    dim3 grid(WW / TILE, HH / TILE);
    gf_pass1<<<grid, 256, 0, stream>>>(x, ab);
    gf_pass2<<<grid, 256, 0, stream>>>(x, ab, out);
}

// Round 2
// 400.713 us; speedup vs baseline: 1.0791x; 1.0791x over previous
//
#include <hip/hip_runtime.h>
#include <hip/hip_fp16.h>

// PostGammaDenoise fused single-kernel guided filter, r=8 (17x17 box), eps=0.005.
// Halo-recompute: each block computes a,b in a 16px halo from scratch (exact
// under reflect padding, since the reflect extension of Y is symmetric).
// Tile: 32 wide x 64 tall output; staging 64 wide x 96 tall.
// LDS reuse: sY (96x65 f32) -> ab (80x49 half2); hI/hII (96x49) -> hA/hB (80x33).
// Total LDS 62,592 B -> 2 blocks/CU, 8 waves/CU.

#define HH 4096
#define WW 4096
#define TW 32            // output tile width
#define TH 64            // output tile height
#define SW 64            // staged cols  = TW + 32
#define SH 96            // staged rows  = TH + 32
#define SYS 65           // sY stride (+1 pad: <=2-way bank aliasing)
#define HIS 49           // hI/hII/ab stride
#define HAS 33           // hA/hB stride
#define INV289 (1.0f / 289.0f)
#define EPSV 0.005f

__device__ __forceinline__ int reflect_idx(int i, int n) {
    i = (i < 0) ? -i : i;
    i = (i >= n) ? (2 * n - 2 - i) : i;
    return i;
}

__global__ __launch_bounds__(256) void gf_fused(const float* __restrict__ x,
                                                float* __restrict__ out) {
    __shared__ float sY[SH * SYS];    // 24,960 B
    __shared__ float hI[SH * HIS];    // 18,816 B
    __shared__ float hII[SH * HIS];   // 18,816 B
    const int t = threadIdx.x;
    const int tx = blockIdx.x * TW;
    const int ty = blockIdx.y * TH;

    // ---- Phase A: stage luma for the 96x64 halo region ----
    const bool interior = (tx >= 16) & (tx + 48 <= WW) & (ty >= 16) & (ty + 80 <= HH);
    if (interior) {
        for (int idx = t; idx < SH * SW; idx += 256) {
            int r = idx >> 6, c = idx & 63;
            const float* p = x + (((ty + r - 16) * WW) + (tx + c - 16)) * 3;
            sY[r * SYS + c] = 0.2126f * p[0] + 0.7152f * p[1] + 0.0722f * p[2];
        }
    } else {
        for (int idx = t; idx < SH * SW; idx += 256) {
            int r = idx >> 6, c = idx & 63;
            int gy = reflect_idx(ty + r - 16, HH);
            int gx = reflect_idx(tx + c - 16, WW);
            const float* p = x + (gy * WW + gx) * 3;
            sY[r * SYS + c] = 0.2126f * p[0] + 0.7152f * p[1] + 0.0722f * p[2];
        }
    }
    __syncthreads();

    // ---- Phase B: horizontal box17 of (Y, Y^2): 96 rows x 48 out cols ----
    // task -> (r = task % 96, seg = task / 96); consecutive lanes = consecutive
    // rows (stride 65/49 odd -> <=2-way bank aliasing).
    for (int task = t; task < SH * 3; task += 256) {
        int r = task % SH;
        int s = task / SH;
        int base = r * SYS + s * 16;
        int ob = r * HIS + s * 16;
        float sI = 0.f, sII = 0.f;
        #pragma unroll
        for (int k = 0; k <= 16; ++k) { float w = sY[base + k]; sI += w; sII += w * w; }
        hI[ob] = sI; hII[ob] = sII;
        #pragma unroll
        for (int j = 1; j < 16; ++j) {
            float va = sY[base + 16 + j];
            float vs = sY[base + j - 1];
            sI  += va - vs;
            sII += va * va - vs * vs;
            hI[ob + j] = sI; hII[ob + j] = sII;
        }
    }
    __syncthreads();

    // ---- Phase C: vertical box17 + a,b (80 rows x 48 cols), half2 into sY ----
    __half2* ab = (__half2*)sY;
    if (t < 240) {
        int c = t % 48;
        int q = t / 48;          // 0..4, 16 rows each
        int r0 = q * 16;
        float sI = 0.f, sII = 0.f;
        #pragma unroll
        for (int k = 0; k <= 16; ++k) {
            sI  += hI[(r0 + k) * HIS + c];
            sII += hII[(r0 + k) * HIS + c];
        }
        #pragma unroll
        for (int j = 0; j < 16; ++j) {
            int o = r0 + j;
            float mI = sI * INV289;
            float mII = sII * INV289;
            float var = mII - mI * mI;
            float a = var / (var + EPSV);
            float b = mI - a * mI;
            ab[o * HIS + c] = __floats2half2_rn(a, b);
            if (j < 15) {
                sI  += hI[(o + 17) * HIS + c] - hI[o * HIS + c];
                sII += hII[(o + 17) * HIS + c] - hII[o * HIS + c];
            }
        }
    }
    __syncthreads();

    // ---- Phase D: horizontal box17 of (a,b): 80 rows x 32 out cols ----
    float* hA = hI;
    float* hB = hII;
    if (t < 160) {
        int r = t % 80;
        int s = t / 80;          // 0..1
        int base = r * HIS + s * 16;
        int ob = r * HAS + s * 16;
        float sA = 0.f, sB = 0.f;
        #pragma unroll
        for (int k = 0; k <= 16; ++k) {
            float2 v = __half22float2(ab[base + k]);
            sA += v.x; sB += v.y;
        }
        hA[ob] = sA; hB[ob] = sB;
        #pragma unroll
        for (int j = 1; j < 16; ++j) {
            float2 va = __half22float2(ab[base + 16 + j]);
            float2 vs = __half22float2(ab[base + j - 1]);
            sA += va.x - vs.x;
            sB += va.y - vs.y;
            hA[ob + j] = sA; hB[ob + j] = sB;
        }
    }
    __syncthreads();

    // ---- Phase E: vertical box17 + epilogue (64 rows x 32 cols) ----
    {
        int c = t & 31;
        int q = t >> 5;          // 0..7, 8 rows each
        int r0 = q * 8;
        float sA = 0.f, sB = 0.f;
        #pragma unroll
        for (int k = 0; k <= 16; ++k) {
            sA += hA[(r0 + k) * HAS + c];
            sB += hB[(r0 + k) * HAS + c];
        }
        #pragma unroll
        for (int j = 0; j < 8; ++j) {
            int o = r0 + j;
            float ma = sA * INV289;
            float mb = sB * INV289;
            int gy = ty + o, gx = tx + c;
            const float* p = x + (gy * WW + gx) * 3;
            float rr = p[0], gg = p[1], bb = p[2];
            float Y = 0.2126f * rr + 0.7152f * gg + 0.0722f * bb;
            float scale = (ma * Y + mb) / fmaxf(Y, 1e-6f);
            float* qo = out + (gy * WW + gx) * 3;
            qo[0] = fminf(fmaxf(rr * scale, 0.f), 1.f);
            qo[1] = fminf(fmaxf(gg * scale, 0.f), 1.f);
            qo[2] = fminf(fmaxf(bb * scale, 0.f), 1.f);
            if (j < 7) {
                sA += hA[(o + 17) * HAS + c] - hA[o * HAS + c];
                sB += hB[(o + 17) * HAS + c] - hB[o * HAS + c];
            }
        }
    }
}

extern "C" void kernel_launch(void* const* d_in, const int* in_sizes, int n_in,
                              void* d_out, int out_size, void* d_ws, size_t ws_size,
                              hipStream_t stream) {
    const float* x = (const float*)d_in[0];
    float* out = (float*)d_out;
    dim3 grid(WW / TW, HH / TH);   // 128 x 64 = 8192 blocks
    gf_fused<<<grid, 256, 0, stream>>>(x, out);
}

// Round 3
// 397.685 us; speedup vs baseline: 1.0873x; 1.0076x over previous
//
#include <hip/hip_runtime.h>
#include <hip/hip_fp16.h>

// PostGammaDenoise fused single-kernel guided filter, r=8 (17x17 box), eps=0.005.
// Halo-recompute (exact under reflect padding). Tile 32x64 out, staged 64x96.
// LDS compression for occupancy: Y staged fp16, (hI,hII) and (hA,hB) packed
// half2, buffers overlaid across barriers. Total 34,496 B -> 4 blocks/CU,
// 16 waves/CU (was 62,976 B -> 2 blocks/CU, latency-bound at 22% occupancy).
// Epilogue recomputes Y from x in f32, so fp16 only perturbs box sums
// (analysis: Delta Y_smooth ~6e-4 << 0.02 threshold).

#define HH 4096
#define WW 4096
#define TW 32            // output tile width
#define TH 64            // output tile height
#define SW 64            // staged cols = TW + 32
#define SH 96            // staged rows = TH + 32
#define SYS 65           // sY stride in halfs   (odd -> <=2-way bank aliasing)
#define HIS 49           // hIhII/ab stride in half2s (odd dwords -> conflict-free)
#define HAS 33           // hAhB stride in half2s
#define INV289 (1.0f / 289.0f)
#define EPSV 0.005f

__device__ __forceinline__ int reflect_idx(int i, int n) {
    i = (i < 0) ? -i : i;
    i = (i >= n) ? (2 * n - 2 - i) : i;
    return i;
}

__global__ __launch_bounds__(256, 4) void gf_fused(const float* __restrict__ x,
                                                   float* __restrict__ out) {
    // 34,496 B total:
    //   [0,      15680): sY (96x65 halfs, 12480 B; dead after B) / ab (80x49 half2, written in C)
    //   [15680,  34496): hIhII (96x49 half2; dead after C) / hAhB (80x33 half2, written in D)
    __shared__ __align__(16) char smem[15680 + 18816];
    __half*  sY    = (__half*)smem;
    __half2* ab    = (__half2*)smem;
    __half2* hIhII = (__half2*)(smem + 15680);
    __half2* hAhB  = (__half2*)(smem + 15680);

    const int t = threadIdx.x;
    const int tx = blockIdx.x * TW;
    const int ty = blockIdx.y * TH;

    // ---- Phase A: stage luma (fp16) for the 96x64 halo region ----
    {
        const int c  = t & 63;      // column: fixed per thread
        const int r0 = t >> 6;      // starting row 0..3, step 4
        const bool interior = (tx >= 16) & (tx + 48 <= WW) & (ty >= 16) & (ty + 80 <= HH);
        if (interior) {
            const float* p = x + ((long)(ty + r0 - 16) * WW + (tx + c - 16)) * 3;
            for (int r = r0; r < SH; r += 4, p += 4 * WW * 3) {
                float Yv = 0.2126f * p[0] + 0.7152f * p[1] + 0.0722f * p[2];
                sY[r * SYS + c] = __float2half_rn(Yv);
            }
        } else {
            const int gx = reflect_idx(tx + c - 16, WW);
            for (int r = r0; r < SH; r += 4) {
                int gy = reflect_idx(ty + r - 16, HH);
                const float* p = x + ((long)gy * WW + gx) * 3;
                float Yv = 0.2126f * p[0] + 0.7152f * p[1] + 0.0722f * p[2];
                sY[r * SYS + c] = __float2half_rn(Yv);
            }
        }
    }
    __syncthreads();

    // ---- Phase B: horizontal box17 of (Y, Y^2): 96 rows x 3 segs of 16 ----
    for (int task = t; task < SH * 3; task += 256) {
        int r = task % SH;
        int s = task / SH;
        int base = r * SYS + s * 16;
        int ob = r * HIS + s * 16;
        float sI = 0.f, sII = 0.f;
        #pragma unroll
        for (int k = 0; k <= 16; ++k) {
            float w = __half2float(sY[base + k]);
            sI += w; sII += w * w;
        }
        hIhII[ob] = __floats2half2_rn(sI, sII);
        #pragma unroll
        for (int j = 1; j < 16; ++j) {
            float va = __half2float(sY[base + 16 + j]);
            float vs = __half2float(sY[base + j - 1]);
            sI  += va - vs;
            sII += va * va - vs * vs;
            hIhII[ob + j] = __floats2half2_rn(sI, sII);
        }
    }
    __syncthreads();

    // ---- Phase C: vertical box17 + a,b (80 rows x 48 cols) -> ab (over sY) ----
    if (t < 240) {
        int c = t % 48;
        int q = t / 48;          // 0..4, 16 rows each
        int r0 = q * 16;
        float sI = 0.f, sII = 0.f;
        #pragma unroll
        for (int k = 0; k <= 16; ++k) {
            float2 v = __half22float2(hIhII[(r0 + k) * HIS + c]);
            sI += v.x; sII += v.y;
        }
        #pragma unroll
        for (int j = 0; j < 16; ++j) {
            int o = r0 + j;
            float mI = sI * INV289;
            float mII = sII * INV289;
            float var = mII - mI * mI;
            float a = var / (var + EPSV);
            float b = mI - a * mI;
            ab[o * HIS + c] = __floats2half2_rn(a, b);
            if (j < 15) {
                float2 va = __half22float2(hIhII[(o + 17) * HIS + c]);
                float2 vs = __half22float2(hIhII[o * HIS + c]);
                sI  += va.x - vs.x;
                sII += va.y - vs.y;
            }
        }
    }
    __syncthreads();

    // ---- Phase D: horizontal box17 of (a,b): 80 rows x 2 segs -> hAhB (over hIhII) ----
    if (t < 160) {
        int r = t % 80;
        int s = t / 80;          // 0..1
        int base = r * HIS + s * 16;
        int ob = r * HAS + s * 16;
        float sA = 0.f, sB = 0.f;
        #pragma unroll
        for (int k = 0; k <= 16; ++k) {
            float2 v = __half22float2(ab[base + k]);
            sA += v.x; sB += v.y;
        }
        hAhB[ob] = __floats2half2_rn(sA, sB);
        #pragma unroll
        for (int j = 1; j < 16; ++j) {
            float2 va = __half22float2(ab[base + 16 + j]);
            float2 vs = __half22float2(ab[base + j - 1]);
            sA += va.x - vs.x;
            sB += va.y - vs.y;
            hAhB[ob + j] = __floats2half2_rn(sA, sB);
        }
    }
    __syncthreads();

    // ---- Phase E: vertical box17 + epilogue (64 rows x 32 cols) ----
    {
        int c = t & 31;
        int q = t >> 5;          // 0..7, 8 rows each
        int r0 = q * 8;
        float sA = 0.f, sB = 0.f;
        #pragma unroll
        for (int k = 0; k <= 16; ++k) {
            float2 v = __half22float2(hAhB[(r0 + k) * HAS + c]);
            sA += v.x; sB += v.y;
        }
        #pragma unroll
        for (int j = 0; j < 8; ++j) {
            int o = r0 + j;
            float ma = sA * INV289;
            float mb = sB * INV289;
            int gy = ty + o, gx = tx + c;
            const float* p = x + ((long)gy * WW + gx) * 3;
            float rr = p[0], gg = p[1], bb = p[2];
            float Y = 0.2126f * rr + 0.7152f * gg + 0.0722f * bb;
            float scale = (ma * Y + mb) / fmaxf(Y, 1e-6f);
            float* qo = out + ((long)gy * WW + gx) * 3;
            qo[0] = fminf(fmaxf(rr * scale, 0.f), 1.f);
            qo[1] = fminf(fmaxf(gg * scale, 0.f), 1.f);
            qo[2] = fminf(fmaxf(bb * scale, 0.f), 1.f);
            if (j < 7) {
                float2 va = __half22float2(hAhB[(o + 17) * HAS + c]);
                float2 vs = __half22float2(hAhB[o * HAS + c]);
                sA += va.x - vs.x;
                sB += va.y - vs.y;
            }
        }
    }
}

extern "C" void kernel_launch(void* const* d_in, const int* in_sizes, int n_in,
                              void* d_out, int out_size, void* d_ws, size_t ws_size,
                              hipStream_t stream) {
    const float* x = (const float*)d_in[0];
    float* out = (float*)d_out;
    dim3 grid(WW / TW, HH / TH);   // 128 x 64 = 8192 blocks
    gf_fused<<<grid, 256, 0, stream>>>(x, out);
}